// Round 1
// baseline (200.250 us; speedup 1.0000x reference)
//
#include <hip/hip_runtime.h>
#include <hip/hip_bf16.h>
#include <math.h>
#include <stdint.h>

#define L_SEQ 4096
#define NB 2
#define NH 16
#define DHEAD 64
#define DM 1024

typedef __bf16 bf16_t;
typedef __attribute__((ext_vector_type(8))) __bf16 bf16x8;
typedef __attribute__((ext_vector_type(4))) float f32x4;

#define GLD16(gp, lp) __builtin_amdgcn_global_load_lds(                          \
    (const __attribute__((address_space(1))) void*)(gp),                         \
    (__attribute__((address_space(3))) void*)(lp), 16, 0, 0)

// ---------------- cast fp32 -> bf16, 8 elems/thread ----------------
__global__ __launch_bounds__(256) void cast_f2b_kernel(const float* __restrict__ in,
                                                       bf16_t* __restrict__ out, int n8)
{
    int t = blockIdx.x * 256 + threadIdx.x;
    if (t >= n8) return;
    const f32x4* ip = (const f32x4*)(in + (size_t)t * 8);
    f32x4 a = ip[0], b = ip[1];
    bf16x8 o;
    o[0] = (__bf16)a[0]; o[1] = (__bf16)a[1]; o[2] = (__bf16)a[2]; o[3] = (__bf16)a[3];
    o[4] = (__bf16)b[0]; o[5] = (__bf16)b[1]; o[6] = (__bf16)b[2]; o[7] = (__bf16)b[3];
    *(bf16x8*)(out + (size_t)t * 8) = o;
}

// ---------------- conn[h][w]: per-head positional MLP + softmax ----------------
__device__ __forceinline__ float gelu_exact(float z)
{
    return 0.5f * z * (1.0f + erff(z * 0.7071067811865475f));
}

__global__ void conn_kernel(const float* __restrict__ cw1, const float* __restrict__ cb1,
                            const float* __restrict__ cw2, const float* __restrict__ cb2,
                            const float* __restrict__ cw3, const float* __restrict__ cb3,
                            float* __restrict__ conn)
{
    const int h = blockIdx.x;     // 16 blocks
    const int j = threadIdx.x;    // 32 threads
    __shared__ float h1[7][32];
    __shared__ float h2[7][32];

    for (int w = 0; w < 7; ++w) {
        float pos = (float)w / 6.0f;
        float z = pos * cw1[h * 32 + j] + cb1[h * 32 + j];
        h1[w][j] = gelu_exact(z);
    }
    __syncthreads();
    for (int w = 0; w < 7; ++w) {
        float z = cb2[h * 32 + j];
        for (int i = 0; i < 32; ++i) z += h1[w][i] * cw2[((size_t)h * 32 + j) * 32 + i];
        h2[w][j] = gelu_exact(z);
    }
    __syncthreads();
    if (j == 0) {
        float cwt[7];
        float mx = -1e30f;
        for (int w = 0; w < 7; ++w) {
            float z = cb3[h];
            for (int i = 0; i < 32; ++i) z += h2[w][i] * cw3[h * 32 + i];
            cwt[w] = z;
            mx = fmaxf(mx, z);
        }
        float Z = 0.0f;
        for (int w = 0; w < 7; ++w) { cwt[w] = expf(cwt[w] - mx); Z += cwt[w]; }
        for (int w = 0; w < 7; ++w) conn[h * 7 + w] = cwt[w] / Z;
    }
}

// ---------------- bf16 GEMM: C[M,N] = A[M,K] @ B[N,K]^T (+bias) ----------------
// m97 structure: 128x128 tile, BK=64, 4 waves (2x2 of 64x64), linear LDS,
// global_load_lds width=16, 2 barriers per K-step.
template<bool F32OUT, bool BIAS>
__global__ __launch_bounds__(256) void gemm_bt(const bf16_t* __restrict__ A,
                                               const bf16_t* __restrict__ Bw,
                                               void* __restrict__ Cout,
                                               const float* __restrict__ bias,
                                               int M, int N, int K)
{
    __shared__ bf16_t lA[128 * 64];
    __shared__ bf16_t lB[128 * 64];
    const int tid  = threadIdx.x;
    const int lane = tid & 63;
    const int wave = tid >> 6;
    const int wm = (wave >> 1) * 64;
    const int wn = (wave & 1) * 64;
    const int bm = blockIdx.x * 128;
    const int bn = blockIdx.y * 128;

    f32x4 acc[4][4] = {};

    // staging: thread t covers LDS bytes [t*16, t*16+16) (+it*4096)
    const int srow = tid >> 3;            // 0..31
    const int scol = (tid & 7) * 8;       // k-element offset
    const bf16_t* Ap = A + (size_t)(bm + srow) * K + scol;
    const bf16_t* Bp = Bw + (size_t)(bn + srow) * K + scol;
    char* lAbase = (char*)lA + wave * 1024;   // wave-uniform LDS base
    char* lBbase = (char*)lB + wave * 1024;

    for (int k0 = 0; k0 < K; k0 += 64) {
#pragma unroll
        for (int it = 0; it < 4; ++it) {
            GLD16(Ap + (size_t)(it * 32) * K + k0, lAbase + it * 4096);
            GLD16(Bp + (size_t)(it * 32) * K + k0, lBbase + it * 4096);
        }
        __syncthreads();   // drains vmcnt before compute
#pragma unroll
        for (int kk = 0; kk < 2; ++kk) {
            bf16x8 af[4], bfr[4];
            const int c = kk * 32 + (lane >> 4) * 8;
#pragma unroll
            for (int i = 0; i < 4; ++i) {
                af[i]  = *(const bf16x8*)&lA[(wm + i * 16 + (lane & 15)) * 64 + c];
                bfr[i] = *(const bf16x8*)&lB[(wn + i * 16 + (lane & 15)) * 64 + c];
            }
#pragma unroll
            for (int i = 0; i < 4; ++i)
#pragma unroll
                for (int j = 0; j < 4; ++j)
                    acc[i][j] = __builtin_amdgcn_mfma_f32_16x16x32_bf16(af[i], bfr[j], acc[i][j], 0, 0, 0);
        }
        __syncthreads();   // before overwriting LDS next iter
    }

    // epilogue: C/D frag layout col=lane&15, row=(lane>>4)*4+reg  [m89-verified]
    const int r0 = (lane >> 4) * 4;
    const int c0 = lane & 15;
#pragma unroll
    for (int i = 0; i < 4; ++i) {
#pragma unroll
        for (int j = 0; j < 4; ++j) {
            const int col = bn + wn + j * 16 + c0;
            float bv = BIAS ? bias[col] : 0.0f;
#pragma unroll
            for (int r = 0; r < 4; ++r) {
                const int row = bm + wm + i * 16 + r0 + r;
                float v = acc[i][j][r] + bv;
                if (F32OUT) ((float*)Cout)[(size_t)row * N + col] = v;
                else        ((bf16_t*)Cout)[(size_t)row * N + col] = (__bf16)v;
            }
        }
    }
}

// ---------------- windowed attention: one thread per (b,h,l) ----------------
__global__ __launch_bounds__(256) void attn_win_kernel(const bf16_t* __restrict__ Q,
                                                       const bf16_t* __restrict__ K,
                                                       const bf16_t* __restrict__ V,
                                                       const float* __restrict__ conn,
                                                       bf16_t* __restrict__ AO)
{
    const int gid = blockIdx.x * 256 + threadIdx.x;   // 0 .. B*H*L-1
    const int l = gid & (L_SEQ - 1);
    const int h = (gid >> 12) & (NH - 1);
    const int b = gid >> 16;
    const size_t row = (size_t)b * L_SEQ + l;
    const bf16_t* qp = Q + row * DM + h * DHEAD;

    bf16x8 qv[8];
#pragma unroll
    for (int i = 0; i < 8; ++i) qv[i] = *(const bf16x8*)(qp + i * 8);

    float s[7];
#pragma unroll
    for (int o = 0; o < 7; ++o) {
        const int lk = l + o - 3;
        float d = 0.0f;
        if (lk >= 0 && lk < L_SEQ) {
            const bf16_t* kp = K + ((size_t)b * L_SEQ + lk) * DM + h * DHEAD;
#pragma unroll
            for (int i = 0; i < 8; ++i) {
                bf16x8 kv = *(const bf16x8*)(kp + i * 8);
#pragma unroll
                for (int j = 0; j < 8; ++j) d += (float)qv[i][j] * (float)kv[j];
            }
        }
        s[o] = d * 0.125f;   // /sqrt(64); zero-padded K rows give score exactly 0
    }

    float mx = s[0];
#pragma unroll
    for (int o = 1; o < 7; ++o) mx = fmaxf(mx, s[o]);
    float e[7], Z = 0.0f;
#pragma unroll
    for (int o = 0; o < 7; ++o) { e[o] = expf(s[o] - mx); Z += e[o]; }

    // fw = (e/Z)*conn; fw /= (sum(fw)+1e-9)  ==  e*conn / (sum(e*conn) + 1e-9*Z)
    float fw[7], fs = 0.0f;
#pragma unroll
    for (int o = 0; o < 7; ++o) { fw[o] = e[o] * conn[h * 7 + o]; fs += fw[o]; }
    const float inv = 1.0f / (fs + 1e-9f * Z);

    float outv[64] = {};
#pragma unroll
    for (int o = 0; o < 7; ++o) {
        const int lk = l + o - 3;
        if (lk < 0 || lk >= L_SEQ) continue;   // zero-padded V rows contribute 0
        const float w = fw[o] * inv;
        const bf16_t* vp = V + ((size_t)b * L_SEQ + lk) * DM + h * DHEAD;
#pragma unroll
        for (int i = 0; i < 8; ++i) {
            bf16x8 vv = *(const bf16x8*)(vp + i * 8);
#pragma unroll
            for (int j = 0; j < 8; ++j) outv[i * 8 + j] += w * (float)vv[j];
        }
    }

    bf16_t* op = AO + row * DM + h * DHEAD;
#pragma unroll
    for (int i = 0; i < 8; ++i) {
        bf16x8 ov;
#pragma unroll
        for (int j = 0; j < 8; ++j) ov[j] = (__bf16)outv[i * 8 + j];
        *(bf16x8*)(op + i * 8) = ov;
    }
}

// ---------------- launch ----------------
extern "C" void kernel_launch(void* const* d_in, const int* in_sizes, int n_in,
                              void* d_out, int out_size, void* d_ws, size_t ws_size,
                              hipStream_t stream)
{
    const float* x   = (const float*)d_in[0];
    const float* wq  = (const float*)d_in[1];
    const float* wk  = (const float*)d_in[2];
    const float* wv  = (const float*)d_in[3];
    const float* wo  = (const float*)d_in[4];
    const float* bo  = (const float*)d_in[5];
    const float* cw1 = (const float*)d_in[6];
    const float* cb1 = (const float*)d_in[7];
    const float* cw2 = (const float*)d_in[8];
    const float* cb2 = (const float*)d_in[9];
    const float* cw3 = (const float*)d_in[10];
    const float* cb3 = (const float*)d_in[11];
    float* out = (float*)d_out;

    char* ws = (char*)d_ws;
    const size_t MB = 1024 * 1024;
    bf16_t* xb   = (bf16_t*)(ws);             // 16 MB; reused as attention output
    bf16_t* wqb  = (bf16_t*)(ws + 16 * MB);   // 2 MB each
    bf16_t* wkb  = (bf16_t*)(ws + 18 * MB);
    bf16_t* wvb  = (bf16_t*)(ws + 20 * MB);
    bf16_t* wob  = (bf16_t*)(ws + 22 * MB);
    bf16_t* Qb   = (bf16_t*)(ws + 24 * MB);   // 16 MB each
    bf16_t* Kb   = (bf16_t*)(ws + 40 * MB);
    bf16_t* Vb   = (bf16_t*)(ws + 56 * MB);
    float*  conn = (float*)(ws + 72 * MB);    // 448 B

    const int Mrows = NB * L_SEQ;             // 8192

    cast_f2b_kernel<<<(Mrows * DM / 8 + 255) / 256, 256, 0, stream>>>(x, xb, Mrows * DM / 8);
    cast_f2b_kernel<<<(DM * DM / 8 + 255) / 256, 256, 0, stream>>>(wq, wqb, DM * DM / 8);
    cast_f2b_kernel<<<(DM * DM / 8 + 255) / 256, 256, 0, stream>>>(wk, wkb, DM * DM / 8);
    cast_f2b_kernel<<<(DM * DM / 8 + 255) / 256, 256, 0, stream>>>(wv, wvb, DM * DM / 8);
    cast_f2b_kernel<<<(DM * DM / 8 + 255) / 256, 256, 0, stream>>>(wo, wob, DM * DM / 8);

    conn_kernel<<<NH, 32, 0, stream>>>(cw1, cb1, cw2, cb2, cw3, cb3, conn);

    dim3 g(Mrows / 128, DM / 128);
    gemm_bt<false, false><<<g, 256, 0, stream>>>(xb, wqb, Qb, nullptr, Mrows, DM, DM);
    gemm_bt<false, false><<<g, 256, 0, stream>>>(xb, wkb, Kb, nullptr, Mrows, DM, DM);
    gemm_bt<false, false><<<g, 256, 0, stream>>>(xb, wvb, Vb, nullptr, Mrows, DM, DM);

    attn_win_kernel<<<(NB * NH * L_SEQ) / 256, 256, 0, stream>>>(Qb, Kb, Vb, conn, xb);

    gemm_bt<true, true><<<g, 256, 0, stream>>>(xb, wob, out, bo, Mrows, DM, DM);
}

// Round 2
// 157.413 us; speedup vs baseline: 1.2721x; 1.2721x over previous
//
#include <hip/hip_runtime.h>
#include <hip/hip_bf16.h>
#include <math.h>
#include <stdint.h>

#define L_SEQ 4096
#define NB 2
#define NH 16
#define DHEAD 64
#define DM 1024
#define DQKV 3072

typedef __bf16 bf16_t;
typedef __attribute__((ext_vector_type(8))) __bf16 bf16x8;
typedef __attribute__((ext_vector_type(4))) float f32x4;

#define GLD16(gp, lp) __builtin_amdgcn_global_load_lds(                          \
    (const __attribute__((address_space(1))) void*)(gp),                         \
    (__attribute__((address_space(3))) void*)(lp), 16, 0, 0)

// ---------------- cast fp32 -> bf16, 8 elems/thread ----------------
__global__ __launch_bounds__(256) void cast_f2b_kernel(const float* __restrict__ in,
                                                       bf16_t* __restrict__ out, int n8)
{
    int t = blockIdx.x * 256 + threadIdx.x;
    if (t >= n8) return;
    const f32x4* ip = (const f32x4*)(in + (size_t)t * 8);
    f32x4 a = ip[0], b = ip[1];
    bf16x8 o;
    o[0] = (__bf16)a[0]; o[1] = (__bf16)a[1]; o[2] = (__bf16)a[2]; o[3] = (__bf16)a[3];
    o[4] = (__bf16)b[0]; o[5] = (__bf16)b[1]; o[6] = (__bf16)b[2]; o[7] = (__bf16)b[3];
    *(bf16x8*)(out + (size_t)t * 8) = o;
}

// fused cast of wq|wk|wv into one [3072][1024] bf16 buffer
__global__ __launch_bounds__(256) void cast_w3_kernel(const float* __restrict__ wq,
                                                      const float* __restrict__ wk,
                                                      const float* __restrict__ wv,
                                                      bf16_t* __restrict__ out)
{
    int t = blockIdx.x * 256 + threadIdx.x;      // 0 .. 3*131072-1
    const int n1 = DM * DM / 8;                  // 131072
    const float* src; int lt;
    if (t < n1)          { src = wq; lt = t; }
    else if (t < 2 * n1) { src = wk; lt = t - n1; }
    else                 { src = wv; lt = t - 2 * n1; }
    const f32x4* ip = (const f32x4*)(src + (size_t)lt * 8);
    f32x4 a = ip[0], b = ip[1];
    bf16x8 o;
    o[0] = (__bf16)a[0]; o[1] = (__bf16)a[1]; o[2] = (__bf16)a[2]; o[3] = (__bf16)a[3];
    o[4] = (__bf16)b[0]; o[5] = (__bf16)b[1]; o[6] = (__bf16)b[2]; o[7] = (__bf16)b[3];
    *(bf16x8*)(out + (size_t)t * 8) = o;
}

// ---------------- conn[h][w]: per-head positional MLP + softmax ----------------
__device__ __forceinline__ float gelu_exact(float z)
{
    return 0.5f * z * (1.0f + erff(z * 0.7071067811865475f));
}

__global__ void conn_kernel(const float* __restrict__ cw1, const float* __restrict__ cb1,
                            const float* __restrict__ cw2, const float* __restrict__ cb2,
                            const float* __restrict__ cw3, const float* __restrict__ cb3,
                            float* __restrict__ conn)
{
    const int h = blockIdx.x;     // 16 blocks
    const int j = threadIdx.x;    // 32 threads
    __shared__ float h1[7][32];
    __shared__ float h2[7][32];

    for (int w = 0; w < 7; ++w) {
        float pos = (float)w / 6.0f;
        float z = pos * cw1[h * 32 + j] + cb1[h * 32 + j];
        h1[w][j] = gelu_exact(z);
    }
    __syncthreads();
    for (int w = 0; w < 7; ++w) {
        float z = cb2[h * 32 + j];
        for (int i = 0; i < 32; ++i) z += h1[w][i] * cw2[((size_t)h * 32 + j) * 32 + i];
        h2[w][j] = gelu_exact(z);
    }
    __syncthreads();
    if (j == 0) {
        float cwt[7];
        float mx = -1e30f;
        for (int w = 0; w < 7; ++w) {
            float z = cb3[h];
            for (int i = 0; i < 32; ++i) z += h2[w][i] * cw3[h * 32 + i];
            cwt[w] = z;
            mx = fmaxf(mx, z);
        }
        float Z = 0.0f;
        for (int w = 0; w < 7; ++w) { cwt[w] = expf(cwt[w] - mx); Z += cwt[w]; }
        for (int w = 0; w < 7; ++w) conn[h * 7 + w] = cwt[w] / Z;
    }
}

// ---------------- bf16 GEMM: C[M,N] = A[M,K] @ B[N,K]^T (+bias) ----------------
// m97 structure: 128x128 tile, BK=64, 4 waves (2x2 of 64x64), linear LDS,
// global_load_lds width=16, 2 barriers per K-step. XCD-swizzled block id.
// ASSUMES gridDim.x == 64 (M = 8192) and (gridDim.x*gridDim.y) % 8 == 0.
template<bool F32OUT, bool BIAS>
__global__ __launch_bounds__(256) void gemm_bt(const bf16_t* __restrict__ A,
                                               const bf16_t* __restrict__ Bw,
                                               void* __restrict__ Cout,
                                               const float* __restrict__ bias,
                                               int M, int N, int K)
{
    __shared__ bf16_t lA[128 * 64];
    __shared__ bf16_t lB[128 * 64];
    const int tid  = threadIdx.x;
    const int lane = tid & 63;
    const int wave = tid >> 6;
    const int wm = (wave >> 1) * 64;
    const int wn = (wave & 1) * 64;

    // XCD-aware bijective swizzle (nwg % 8 == 0 in all our launches)
    const int nwg = gridDim.x * gridDim.y;
    int id = blockIdx.y * gridDim.x + blockIdx.x;
    id = (id & 7) * (nwg >> 3) + (id >> 3);
    const int bm = (id & 63) << 7;        // gridDim.x == 64
    const int bn = (id >> 6) << 7;

    f32x4 acc[4][4] = {};

    const int srow = tid >> 3;            // 0..31
    const int scol = (tid & 7) * 8;       // k-element offset
    const bf16_t* Ap = A + (size_t)(bm + srow) * K + scol;
    const bf16_t* Bp = Bw + (size_t)(bn + srow) * K + scol;
    char* lAbase = (char*)lA + wave * 1024;   // wave-uniform LDS base
    char* lBbase = (char*)lB + wave * 1024;

    for (int k0 = 0; k0 < K; k0 += 64) {
#pragma unroll
        for (int it = 0; it < 4; ++it) {
            GLD16(Ap + (size_t)(it * 32) * K + k0, lAbase + it * 4096);
            GLD16(Bp + (size_t)(it * 32) * K + k0, lBbase + it * 4096);
        }
        __syncthreads();
#pragma unroll
        for (int kk = 0; kk < 2; ++kk) {
            bf16x8 af[4], bfr[4];
            const int c = kk * 32 + (lane >> 4) * 8;
#pragma unroll
            for (int i = 0; i < 4; ++i) {
                af[i]  = *(const bf16x8*)&lA[(wm + i * 16 + (lane & 15)) * 64 + c];
                bfr[i] = *(const bf16x8*)&lB[(wn + i * 16 + (lane & 15)) * 64 + c];
            }
#pragma unroll
            for (int i = 0; i < 4; ++i)
#pragma unroll
                for (int j = 0; j < 4; ++j)
                    acc[i][j] = __builtin_amdgcn_mfma_f32_16x16x32_bf16(af[i], bfr[j], acc[i][j], 0, 0, 0);
        }
        __syncthreads();
    }

    const int r0 = (lane >> 4) * 4;
    const int c0 = lane & 15;
#pragma unroll
    for (int i = 0; i < 4; ++i) {
#pragma unroll
        for (int j = 0; j < 4; ++j) {
            const int col = bn + wn + j * 16 + c0;
            float bv = BIAS ? bias[col] : 0.0f;
#pragma unroll
            for (int r = 0; r < 4; ++r) {
                const int row = bm + wm + i * 16 + r0 + r;
                float v = acc[i][j][r] + bv;
                if (F32OUT) ((float*)Cout)[(size_t)row * N + col] = v;
                else        ((bf16_t*)Cout)[(size_t)row * N + col] = (__bf16)v;
            }
        }
    }
}

// ---------------- windowed attention: 8 threads per (b,h,l), one per d-chunk ----------------
// QKV layout: [B*L][3072], cols 0-1023 = Q, 1024-2047 = K, 2048-3071 = V.
__global__ __launch_bounds__(256) void attn_win_kernel(const bf16_t* __restrict__ QKV,
                                                       const float* __restrict__ conn,
                                                       bf16_t* __restrict__ AO)
{
    const int t  = threadIdx.x;
    const int ll = t >> 3;                 // 0..31 local l
    const int c  = t & 7;                  // d-chunk
    const int blk  = blockIdx.x;           // 0 .. B*H*(L/32)-1 = 4095
    const int lblk = blk & (L_SEQ / 32 - 1);
    const int h    = (blk >> 7) & (NH - 1);
    const int b    = blk >> 11;
    const int l    = lblk * 32 + ll;
    const size_t row = (size_t)b * L_SEQ + l;

    const bf16x8 qv = *(const bf16x8*)(QKV + row * DQKV + h * DHEAD + c * 8);

    float s[7];
#pragma unroll
    for (int o = 0; o < 7; ++o) {
        const int lk = l + o - 3;
        float d = 0.0f;
        if ((unsigned)lk < L_SEQ) {        // uniform across the 8-thread group
            const bf16x8 kv = *(const bf16x8*)(QKV + ((size_t)b * L_SEQ + lk) * DQKV
                                               + DM + h * DHEAD + c * 8);
#pragma unroll
            for (int j = 0; j < 8; ++j) d += (float)qv[j] * (float)kv[j];
        }
        s[o] = d;
    }
    // butterfly reduce across the 8-thread group (lanes differ only in low 3 bits)
#pragma unroll
    for (int m = 1; m < 8; m <<= 1) {
#pragma unroll
        for (int o = 0; o < 7; ++o) s[o] += __shfl_xor(s[o], m, 64);
    }

    float mx = -1e30f;
#pragma unroll
    for (int o = 0; o < 7; ++o) { s[o] *= 0.125f; mx = fmaxf(mx, s[o]); }
    float e[7], Z = 0.0f;
#pragma unroll
    for (int o = 0; o < 7; ++o) { e[o] = expf(s[o] - mx); Z += e[o]; }

    // fw = (e/Z)*conn; fw /= (sum(fw)+1e-9)  ==  e*conn / (sum(e*conn) + 1e-9*Z)
    float fw[7], fs = 0.0f;
#pragma unroll
    for (int o = 0; o < 7; ++o) { fw[o] = e[o] * conn[h * 7 + o]; fs += fw[o]; }
    const float inv = 1.0f / (fs + 1e-9f * Z);

    float outv[8] = {};
#pragma unroll
    for (int o = 0; o < 7; ++o) {
        const int lk = l + o - 3;
        if ((unsigned)lk >= L_SEQ) continue;
        const float w = fw[o] * inv;
        const bf16x8 vv = *(const bf16x8*)(QKV + ((size_t)b * L_SEQ + lk) * DQKV
                                           + 2 * DM + h * DHEAD + c * 8);
#pragma unroll
        for (int j = 0; j < 8; ++j) outv[j] += w * (float)vv[j];
    }

    bf16x8 ov;
#pragma unroll
    for (int j = 0; j < 8; ++j) ov[j] = (__bf16)outv[j];
    *(bf16x8*)(AO + row * DM + h * DHEAD + c * 8) = ov;
}

// ---------------- launch ----------------
extern "C" void kernel_launch(void* const* d_in, const int* in_sizes, int n_in,
                              void* d_out, int out_size, void* d_ws, size_t ws_size,
                              hipStream_t stream)
{
    const float* x   = (const float*)d_in[0];
    const float* wq  = (const float*)d_in[1];
    const float* wk  = (const float*)d_in[2];
    const float* wv  = (const float*)d_in[3];
    const float* wo  = (const float*)d_in[4];
    const float* bo  = (const float*)d_in[5];
    const float* cw1 = (const float*)d_in[6];
    const float* cb1 = (const float*)d_in[7];
    const float* cw2 = (const float*)d_in[8];
    const float* cb2 = (const float*)d_in[9];
    const float* cw3 = (const float*)d_in[10];
    const float* cb3 = (const float*)d_in[11];
    float* out = (float*)d_out;

    char* ws = (char*)d_ws;
    const size_t MB = 1024 * 1024;
    bf16_t* xb    = (bf16_t*)(ws);             // 16 MB; reused as attention output
    bf16_t* wqkvb = (bf16_t*)(ws + 16 * MB);   // 6 MB   [3072][1024]
    bf16_t* wob   = (bf16_t*)(ws + 22 * MB);   // 2 MB
    bf16_t* QKV   = (bf16_t*)(ws + 24 * MB);   // 48 MB  [8192][3072]
    float*  conn  = (float*)(ws + 72 * MB);    // 448 B

    const int Mrows = NB * L_SEQ;              // 8192

    cast_f2b_kernel<<<(Mrows * DM / 8 + 255) / 256, 256, 0, stream>>>(x, xb, Mrows * DM / 8);
    cast_w3_kernel<<<(3 * DM * DM / 8) / 256, 256, 0, stream>>>(wq, wk, wv, wqkvb);
    cast_f2b_kernel<<<(DM * DM / 8 + 255) / 256, 256, 0, stream>>>(wo, wob, DM * DM / 8);

    conn_kernel<<<NH, 32, 0, stream>>>(cw1, cb1, cw2, cb2, cw3, cb3, conn);

    dim3 gq(Mrows / 128, DQKV / 128);          // 64 x 24 = 1536 blocks
    gemm_bt<false, false><<<gq, 256, 0, stream>>>(xb, wqkvb, QKV, nullptr, Mrows, DQKV, DM);

    attn_win_kernel<<<(NB * NH * L_SEQ * 8) / 256, 256, 0, stream>>>(QKV, conn, xb);

    dim3 go(Mrows / 128, DM / 128);            // 64 x 8 = 512 blocks
    gemm_bt<true, true><<<go, 256, 0, stream>>>(xb, wob, out, bo, Mrows, DM, DM);
}

// Round 3
// 140.266 us; speedup vs baseline: 1.4276x; 1.1222x over previous
//
#include <hip/hip_runtime.h>
#include <hip/hip_bf16.h>
#include <math.h>
#include <stdint.h>

#define L_SEQ 4096
#define NB 2
#define NH 16
#define DHEAD 64
#define DM 1024
#define DQKV 3072

typedef __bf16 bf16_t;
typedef __attribute__((ext_vector_type(8))) __bf16 bf16x8;
typedef __attribute__((ext_vector_type(4))) float f32x4;

#define GLD16(gp, lp) __builtin_amdgcn_global_load_lds(                          \
    (const __attribute__((address_space(1))) void*)(gp),                         \
    (__attribute__((address_space(3))) void*)(lp), 16, 0, 0)

template<int N> __device__ __forceinline__ void vmwait() {
    if constexpr (N >= 8)      asm volatile("s_waitcnt vmcnt(8)" ::: "memory");
    else if constexpr (N == 6) asm volatile("s_waitcnt vmcnt(6)" ::: "memory");
    else if constexpr (N == 4) asm volatile("s_waitcnt vmcnt(4)" ::: "memory");
    else if constexpr (N == 3) asm volatile("s_waitcnt vmcnt(3)" ::: "memory");
    else                       asm volatile("s_waitcnt vmcnt(0)" ::: "memory");
}

// ---------------- cast fp32 -> bf16, 8 elems/thread ----------------
__global__ __launch_bounds__(256) void cast_f2b_kernel(const float* __restrict__ in,
                                                       bf16_t* __restrict__ out, int n8)
{
    int t = blockIdx.x * 256 + threadIdx.x;
    if (t >= n8) return;
    const f32x4* ip = (const f32x4*)(in + (size_t)t * 8);
    f32x4 a = ip[0], b = ip[1];
    bf16x8 o;
    o[0] = (__bf16)a[0]; o[1] = (__bf16)a[1]; o[2] = (__bf16)a[2]; o[3] = (__bf16)a[3];
    o[4] = (__bf16)b[0]; o[5] = (__bf16)b[1]; o[6] = (__bf16)b[2]; o[7] = (__bf16)b[3];
    *(bf16x8*)(out + (size_t)t * 8) = o;
}

__global__ __launch_bounds__(256) void cast_w3_kernel(const float* __restrict__ wq,
                                                      const float* __restrict__ wk,
                                                      const float* __restrict__ wv,
                                                      bf16_t* __restrict__ out)
{
    int t = blockIdx.x * 256 + threadIdx.x;
    const int n1 = DM * DM / 8;
    const float* src; int lt;
    if (t < n1)          { src = wq; lt = t; }
    else if (t < 2 * n1) { src = wk; lt = t - n1; }
    else                 { src = wv; lt = t - 2 * n1; }
    const f32x4* ip = (const f32x4*)(src + (size_t)lt * 8);
    f32x4 a = ip[0], b = ip[1];
    bf16x8 o;
    o[0] = (__bf16)a[0]; o[1] = (__bf16)a[1]; o[2] = (__bf16)a[2]; o[3] = (__bf16)a[3];
    o[4] = (__bf16)b[0]; o[5] = (__bf16)b[1]; o[6] = (__bf16)b[2]; o[7] = (__bf16)b[3];
    *(bf16x8*)(out + (size_t)t * 8) = o;
}

// ---------------- conn[h][w]: per-head positional MLP + softmax ----------------
__device__ __forceinline__ float gelu_exact(float z)
{
    return 0.5f * z * (1.0f + erff(z * 0.7071067811865475f));
}

__global__ void conn_kernel(const float* __restrict__ cw1, const float* __restrict__ cb1,
                            const float* __restrict__ cw2, const float* __restrict__ cb2,
                            const float* __restrict__ cw3, const float* __restrict__ cb3,
                            float* __restrict__ conn)
{
    const int h = blockIdx.x;
    const int j = threadIdx.x;
    __shared__ float h1[7][32];
    __shared__ float h2[7][32];

    for (int w = 0; w < 7; ++w) {
        float pos = (float)w / 6.0f;
        float z = pos * cw1[h * 32 + j] + cb1[h * 32 + j];
        h1[w][j] = gelu_exact(z);
    }
    __syncthreads();
    for (int w = 0; w < 7; ++w) {
        float z = cb2[h * 32 + j];
        for (int i = 0; i < 32; ++i) z += h1[w][i] * cw2[((size_t)h * 32 + j) * 32 + i];
        h2[w][j] = gelu_exact(z);
    }
    __syncthreads();
    if (j == 0) {
        float cwt[7];
        float mx = -1e30f;
        for (int w = 0; w < 7; ++w) {
            float z = cb3[h];
            for (int i = 0; i < 32; ++i) z += h2[w][i] * cw3[h * 32 + i];
            cwt[w] = z;
            mx = fmaxf(mx, z);
        }
        float Z = 0.0f;
        for (int w = 0; w < 7; ++w) { cwt[w] = expf(cwt[w] - mx); Z += cwt[w]; }
        for (int w = 0; w < 7; ++w) conn[h * 7 + w] = cwt[w] / Z;
    }
}

// ---------------- 256xBN bf16 GEMM, BK=32 quad-buffered, counted vmcnt ----------------
// C[M,N] = A[M,K] @ Bw[N,K]^T (+bias).  8 waves (512 thr).
// BN=256: waves 2Mx4N, per-wave 128x64 (MI=8).  BN=128: waves 4Mx2N, per-wave 64x64 (MI=4).
// LDS: 4 K-tile buffers; A-tile 256x32 bf16 (16KB), B-tile BNx32 (BN*64 B).
// Swizzle: 16B col-slot ^= (row>>1)&3  (involution; pre-swizzled global source,
// swizzled ds_read address -> 2-way banks, free).
// Pipeline: group t consumes buf[t&3], stages tile t+3 into buf[(t+3)&3]=buf[(t-1)&3]
// (freed by group t-1; the top-of-group barrier orders all reads before these writes).
// Per-wave stage ownership => per-wave vmcnt is exact: steady vmcnt(2*LPT) keeps
// tiles t+1,t+2 in flight while draining tile t.  Never vmcnt(0) until the tail.
template<int BN, int KDIM, bool F32OUT, bool BIAS>
__global__ __launch_bounds__(512, 2) void gemm256(const bf16_t* __restrict__ A,
                                                  const bf16_t* __restrict__ Bw,
                                                  void* __restrict__ Cout,
                                                  const float* __restrict__ bias,
                                                  int N)
{
    constexpr int NT   = KDIM / 32;
    constexpr int MI   = (BN == 256) ? 8 : 4;
    constexpr int LPTB = (BN == 256) ? 2 : 1;
    constexpr int LPT  = 2 + LPTB;
    constexpr int ASZ  = 256 * 64;          // bytes per A K-tile buffer
    constexpr int BSZ  = BN * 64;
    constexpr int ABUF = 4 * ASZ;

    extern __shared__ char smem[];

    const int tid  = threadIdx.x;
    const int lane = tid & 63;
    const int wave = tid >> 6;

    int wm, wn, arow, bcol;
    if constexpr (BN == 256) {
        wm = (wave >> 2) * 128; wn = (wave & 3) * 64;
        arow = wm + (wave & 3) * 32;          // 32 rows staged by this wave
        bcol = wn + (wave >> 2) * 32;         // 32 cols
    } else {
        wm = (wave >> 1) * 64;  wn = (wave & 1) * 64;
        arow = wm + (wave & 1) * 32;
        bcol = wn + (wave >> 1) * 16;         // 16 cols
    }

    // T1: XCD-aware bijective swizzle (nwg % 8 == 0; gridDim.x == 32)
    const int nwg = gridDim.x * gridDim.y;
    int id = blockIdx.y * gridDim.x + blockIdx.x;
    id = (id & 7) * (nwg >> 3) + (id >> 3);
    const int bm = (id & 31) * 256;
    const int bn = (id >> 5) * BN;

    // stage-side source pre-swizzle: dest slot lane&3 holds global slot (lane&3)^((lane>>3)&3)
    const int scol  = (((lane & 3) ^ ((lane >> 3) & 3)) * 8);
    const int g_row = lane >> 2;

    auto stageA = [&](int kt) {
#pragma unroll
        for (int r = 0; r < 2; ++r) {
            const bf16_t* g = A + (size_t)(bm + arow + r * 16 + g_row) * KDIM + kt * 32 + scol;
            char* l = smem + (kt & 3) * ASZ + (arow + r * 16) * 64;
            GLD16(g, l);
        }
    };
    auto stageB = [&](int kt) {
#pragma unroll
        for (int r = 0; r < LPTB; ++r) {
            const bf16_t* g = Bw + (size_t)(bn + bcol + r * 16 + g_row) * KDIM + kt * 32 + scol;
            char* l = smem + ABUF + (kt & 3) * BSZ + (bcol + r * 16) * 64;
            GLD16(g, l);
        }
    };

    f32x4 acc[MI][4] = {};

    // prologue: tiles 0,1,2 in flight (3*LPT loads per wave)
    stageA(0); stageB(0);
    stageA(1); stageB(1);
    stageA(2); stageB(2);

    // read-side swizzled fragment address pieces
    const int frow  = lane & 15;
    const int fslot = (((lane >> 4) ^ ((lane >> 1) & 3)) * 16);

    for (int t = 0; t < NT; ++t) {
        if (t < NT - 2)      vmwait<2 * LPT>();
        else if (t == NT - 2) vmwait<LPT>();
        else                 vmwait<0>();
        __builtin_amdgcn_s_barrier();
        asm volatile("" ::: "memory");

        const char* Ab = smem + (t & 3) * ASZ;
        const char* Bb = smem + ABUF + (t & 3) * BSZ;
        const bool st = (t + 3 < NT);

        // ---- phase 0: A frags + B j=0,1 ----
        if (st) stageA(t + 3);
        bf16x8 af[MI], b0, b1;
#pragma unroll
        for (int i = 0; i < MI; ++i)
            af[i] = *(const bf16x8*)(Ab + (wm + i * 16 + frow) * 64 + fslot);
        b0 = *(const bf16x8*)(Bb + (wn + 0 * 16 + frow) * 64 + fslot);
        b1 = *(const bf16x8*)(Bb + (wn + 1 * 16 + frow) * 64 + fslot);
        __builtin_amdgcn_s_setprio(1);
#pragma unroll
        for (int i = 0; i < MI; ++i) {
            acc[i][0] = __builtin_amdgcn_mfma_f32_16x16x32_bf16(af[i], b0, acc[i][0], 0, 0, 0);
            acc[i][1] = __builtin_amdgcn_mfma_f32_16x16x32_bf16(af[i], b1, acc[i][1], 0, 0, 0);
        }
        __builtin_amdgcn_s_setprio(0);

        // ---- phase 1: B j=2,3 ----
        if (st) stageB(t + 3);
        bf16x8 b2, b3;
        b2 = *(const bf16x8*)(Bb + (wn + 2 * 16 + frow) * 64 + fslot);
        b3 = *(const bf16x8*)(Bb + (wn + 3 * 16 + frow) * 64 + fslot);
        __builtin_amdgcn_s_setprio(1);
#pragma unroll
        for (int i = 0; i < MI; ++i) {
            acc[i][2] = __builtin_amdgcn_mfma_f32_16x16x32_bf16(af[i], b2, acc[i][2], 0, 0, 0);
            acc[i][3] = __builtin_amdgcn_mfma_f32_16x16x32_bf16(af[i], b3, acc[i][3], 0, 0, 0);
        }
        __builtin_amdgcn_s_setprio(0);
    }

    // epilogue: C/D frag layout col=lane&15, row=(lane>>4)*4+reg
    const int r0 = (lane >> 4) * 4;
    const int c0 = lane & 15;
#pragma unroll
    for (int i = 0; i < MI; ++i) {
#pragma unroll
        for (int j = 0; j < 4; ++j) {
            const int col = bn + wn + j * 16 + c0;
            float bv = BIAS ? bias[col] : 0.0f;
#pragma unroll
            for (int r = 0; r < 4; ++r) {
                const int row = bm + wm + i * 16 + r0 + r;
                float v = acc[i][j][r] + bv;
                if (F32OUT) ((float*)Cout)[(size_t)row * N + col] = v;
                else        ((bf16_t*)Cout)[(size_t)row * N + col] = (__bf16)v;
            }
        }
    }
}

// ---------------- windowed attention: 8 threads per (b,h,l), one per d-chunk ----------------
__global__ __launch_bounds__(256) void attn_win_kernel(const bf16_t* __restrict__ QKV,
                                                       const float* __restrict__ conn,
                                                       bf16_t* __restrict__ AO)
{
    const int t  = threadIdx.x;
    const int ll = t >> 3;
    const int c  = t & 7;
    const int blk  = blockIdx.x;
    const int lblk = blk & (L_SEQ / 32 - 1);
    const int h    = (blk >> 7) & (NH - 1);
    const int b    = blk >> 11;
    const int l    = lblk * 32 + ll;
    const size_t row = (size_t)b * L_SEQ + l;

    const bf16x8 qv = *(const bf16x8*)(QKV + row * DQKV + h * DHEAD + c * 8);

    float s[7];
#pragma unroll
    for (int o = 0; o < 7; ++o) {
        const int lk = l + o - 3;
        float d = 0.0f;
        if ((unsigned)lk < L_SEQ) {
            const bf16x8 kv = *(const bf16x8*)(QKV + ((size_t)b * L_SEQ + lk) * DQKV
                                               + DM + h * DHEAD + c * 8);
#pragma unroll
            for (int j = 0; j < 8; ++j) d += (float)qv[j] * (float)kv[j];
        }
        s[o] = d;
    }
#pragma unroll
    for (int m = 1; m < 8; m <<= 1) {
#pragma unroll
        for (int o = 0; o < 7; ++o) s[o] += __shfl_xor(s[o], m, 64);
    }

    float mx = -1e30f;
#pragma unroll
    for (int o = 0; o < 7; ++o) { s[o] *= 0.125f; mx = fmaxf(mx, s[o]); }
    float e[7], Z = 0.0f;
#pragma unroll
    for (int o = 0; o < 7; ++o) { e[o] = expf(s[o] - mx); Z += e[o]; }

    float fw[7], fs = 0.0f;
#pragma unroll
    for (int o = 0; o < 7; ++o) { fw[o] = e[o] * conn[h * 7 + o]; fs += fw[o]; }
    const float inv = 1.0f / (fs + 1e-9f * Z);

    float outv[8] = {};
#pragma unroll
    for (int o = 0; o < 7; ++o) {
        const int lk = l + o - 3;
        if ((unsigned)lk >= L_SEQ) continue;
        const float w = fw[o] * inv;
        const bf16x8 vv = *(const bf16x8*)(QKV + ((size_t)b * L_SEQ + lk) * DQKV
                                           + 2 * DM + h * DHEAD + c * 8);
#pragma unroll
        for (int j = 0; j < 8; ++j) outv[j] += w * (float)vv[j];
    }

    bf16x8 ov;
#pragma unroll
    for (int j = 0; j < 8; ++j) ov[j] = (__bf16)outv[j];
    *(bf16x8*)(AO + row * DM + h * DHEAD + c * 8) = ov;
}

// ---------------- launch ----------------
extern "C" void kernel_launch(void* const* d_in, const int* in_sizes, int n_in,
                              void* d_out, int out_size, void* d_ws, size_t ws_size,
                              hipStream_t stream)
{
    const float* x   = (const float*)d_in[0];
    const float* wq  = (const float*)d_in[1];
    const float* wk  = (const float*)d_in[2];
    const float* wv  = (const float*)d_in[3];
    const float* wo  = (const float*)d_in[4];
    const float* bo  = (const float*)d_in[5];
    const float* cw1 = (const float*)d_in[6];
    const float* cb1 = (const float*)d_in[7];
    const float* cw2 = (const float*)d_in[8];
    const float* cb2 = (const float*)d_in[9];
    const float* cw3 = (const float*)d_in[10];
    const float* cb3 = (const float*)d_in[11];
    float* out = (float*)d_out;

    char* ws = (char*)d_ws;
    const size_t MB = 1024 * 1024;
    bf16_t* xb    = (bf16_t*)(ws);             // 16 MB; reused as attention output
    bf16_t* wqkvb = (bf16_t*)(ws + 16 * MB);   // 6 MB   [3072][1024]
    bf16_t* wob   = (bf16_t*)(ws + 22 * MB);   // 2 MB
    bf16_t* QKV   = (bf16_t*)(ws + 24 * MB);   // 48 MB  [8192][3072]
    float*  conn  = (float*)(ws + 72 * MB);    // 448 B

    const int Mrows = NB * L_SEQ;              // 8192

    // opt-in for >64KB dynamic LDS (harmless if unnecessary)
    (void)hipFuncSetAttribute((const void*)gemm256<256, DM, false, false>,
                              hipFuncAttributeMaxDynamicSharedMemorySize, 131072);
    (void)hipFuncSetAttribute((const void*)gemm256<128, DM, true, true>,
                              hipFuncAttributeMaxDynamicSharedMemorySize, 98304);

    cast_f2b_kernel<<<(Mrows * DM / 8 + 255) / 256, 256, 0, stream>>>(x, xb, Mrows * DM / 8);
    cast_w3_kernel<<<(3 * DM * DM / 8) / 256, 256, 0, stream>>>(wq, wk, wv, wqkvb);
    cast_f2b_kernel<<<(DM * DM / 8 + 255) / 256, 256, 0, stream>>>(wo, wob, DM * DM / 8);

    conn_kernel<<<NH, 32, 0, stream>>>(cw1, cb1, cw2, cb2, cw3, cb3, conn);

    dim3 gq(Mrows / 256, DQKV / 256);          // 32 x 12 = 384 blocks
    gemm256<256, DM, false, false><<<gq, 512, 131072, stream>>>(xb, wqkvb, QKV, nullptr, DQKV);

    attn_win_kernel<<<(NB * NH * L_SEQ * 8) / 256, 256, 0, stream>>>(QKV, conn, xb);

    dim3 go(Mrows / 256, DM / 128);            // 32 x 8 = 256 blocks
    gemm256<128, DM, true, true><<<go, 512, 98304, stream>>>(xb, wob, out, bo, DM);
}

// Round 4
// 128.972 us; speedup vs baseline: 1.5527x; 1.0876x over previous
//
#include <hip/hip_runtime.h>
#include <hip/hip_bf16.h>
#include <math.h>
#include <stdint.h>

#define L_SEQ 4096
#define NB 2
#define NH 16
#define DHEAD 64
#define DM 1024
#define DQKV 3072

typedef __bf16 bf16_t;
typedef __attribute__((ext_vector_type(8))) __bf16 bf16x8;
typedef __attribute__((ext_vector_type(4))) float f32x4;

#define GLD16(gp, lp) __builtin_amdgcn_global_load_lds(                          \
    (const __attribute__((address_space(1))) void*)(gp),                         \
    (__attribute__((address_space(3))) void*)(lp), 16, 0, 0)

template<int N> __device__ __forceinline__ void vmwait() {
    if constexpr (N == 6)      asm volatile("s_waitcnt vmcnt(6)" ::: "memory");
    else if constexpr (N == 0) asm volatile("s_waitcnt vmcnt(0)" ::: "memory");
}

// ---------------- cast fp32 -> bf16, 8 elems/thread ----------------
__global__ __launch_bounds__(256) void cast_f2b_kernel(const float* __restrict__ in,
                                                       bf16_t* __restrict__ out, int n8)
{
    int t = blockIdx.x * 256 + threadIdx.x;
    if (t >= n8) return;
    const f32x4* ip = (const f32x4*)(in + (size_t)t * 8);
    f32x4 a = ip[0], b = ip[1];
    bf16x8 o;
    o[0] = (__bf16)a[0]; o[1] = (__bf16)a[1]; o[2] = (__bf16)a[2]; o[3] = (__bf16)a[3];
    o[4] = (__bf16)b[0]; o[5] = (__bf16)b[1]; o[6] = (__bf16)b[2]; o[7] = (__bf16)b[3];
    *(bf16x8*)(out + (size_t)t * 8) = o;
}

__global__ __launch_bounds__(256) void cast_w3_kernel(const float* __restrict__ wq,
                                                      const float* __restrict__ wk,
                                                      const float* __restrict__ wv,
                                                      bf16_t* __restrict__ out)
{
    int t = blockIdx.x * 256 + threadIdx.x;
    const int n1 = DM * DM / 8;
    const float* src; int lt;
    if (t < n1)          { src = wq; lt = t; }
    else if (t < 2 * n1) { src = wk; lt = t - n1; }
    else                 { src = wv; lt = t - 2 * n1; }
    const f32x4* ip = (const f32x4*)(src + (size_t)lt * 8);
    f32x4 a = ip[0], b = ip[1];
    bf16x8 o;
    o[0] = (__bf16)a[0]; o[1] = (__bf16)a[1]; o[2] = (__bf16)a[2]; o[3] = (__bf16)a[3];
    o[4] = (__bf16)b[0]; o[5] = (__bf16)b[1]; o[6] = (__bf16)b[2]; o[7] = (__bf16)b[3];
    *(bf16x8*)(out + (size_t)t * 8) = o;
}

// ---------------- conn[h][w]: per-head positional MLP + softmax ----------------
__device__ __forceinline__ float gelu_exact(float z)
{
    return 0.5f * z * (1.0f + erff(z * 0.7071067811865475f));
}

__global__ void conn_kernel(const float* __restrict__ cw1, const float* __restrict__ cb1,
                            const float* __restrict__ cw2, const float* __restrict__ cb2,
                            const float* __restrict__ cw3, const float* __restrict__ cb3,
                            float* __restrict__ conn)
{
    const int h = blockIdx.x;
    const int j = threadIdx.x;
    __shared__ float h1[7][32];
    __shared__ float h2[7][32];

    for (int w = 0; w < 7; ++w) {
        float pos = (float)w / 6.0f;
        float z = pos * cw1[h * 32 + j] + cb1[h * 32 + j];
        h1[w][j] = gelu_exact(z);
    }
    __syncthreads();
    for (int w = 0; w < 7; ++w) {
        float z = cb2[h * 32 + j];
        for (int i = 0; i < 32; ++i) z += h1[w][i] * cw2[((size_t)h * 32 + j) * 32 + i];
        h2[w][j] = gelu_exact(z);
    }
    __syncthreads();
    if (j == 0) {
        float cwt[7];
        float mx = -1e30f;
        for (int w = 0; w < 7; ++w) {
            float z = cb3[h];
            for (int i = 0; i < 32; ++i) z += h2[w][i] * cw3[h * 32 + i];
            cwt[w] = z;
            mx = fmaxf(mx, z);
        }
        float Z = 0.0f;
        for (int w = 0; w < 7; ++w) { cwt[w] = expf(cwt[w] - mx); Z += cwt[w]; }
        for (int w = 0; w < 7; ++w) conn[h * 7 + w] = cwt[w] / Z;
    }
}

// ---------------- 256x128 bf16 GEMM, BK=64, triple-buffer, counted vmcnt ----------------
// C[M=8192, N=NBN*128] = A @ Bw^T (+bias).  512 thr = 8 waves as 4M x 2N,
// per-wave 64x64 (MI=NJ=4) -> LDS-read bytes/MFMA = 0.5KB (balanced vs MFMA floor).
// LDS: 3 x (A 32KB + B 16KB) = 144KB, 1 block/CU.
// Pipeline: prologue stages tiles 0,1 (6 loads each, block-uniform). Iter t:
// vmcnt(6) [drain tile t, keep t+1 in flight] -> raw s_barrier -> phase kk=0
// {8 ds_read, 16 MFMA} -> phase kk=1 {8 ds_read, stage tile t+2, 16 MFMA}.
// Never vmcnt(0) until the last iter. Stage is pinned after the kk=1 reads by
// sched_barrier(0); buffer (t+2)%3 was last read in iter t-1, >=1 barrier +
// full phase earlier => no LDS write/read race.
// Swizzle: 16B slot s_dest holds global slot s_dest ^ (row&7) (pre-swizzled
// global source); reads use s' = s ^ (row&7)  => balanced banks on ds_read_b128.
template<int NBN, bool F32OUT, bool BIAS>
__global__ __launch_bounds__(512, 2) void gemm3(const bf16_t* __restrict__ A,
                                                const bf16_t* __restrict__ Bw,
                                                void* __restrict__ Cout,
                                                const float* __restrict__ bias)
{
    constexpr int K  = 1024;
    constexpr int NT = K / 64;            // 16
    constexpr int N  = NBN * 128;

    extern __shared__ char smem[];        // A: 3x32KB @0, B: 3x16KB @98304

    const int tid  = threadIdx.x;
    const int lane = tid & 63;
    const int wave = tid >> 6;
    const int wm   = (wave >> 1) * 64;    // 4 M-waves
    const int wn   = (wave & 1) * 64;     // 2 N-waves

    // XCD-aware bijective swizzle; bn-fastest within each XCD chunk so one
    // chunk shares a 4-row-tile A slice (2MB, fits per-XCD L2).
    const int nwg = gridDim.x;            // multiple of 8
    int id = blockIdx.x;
    id = (id & 7) * (nwg >> 3) + (id >> 3);
    const int bm = (id / NBN) * 256;
    const int bn = (id % NBN) * 128;

    // staging: thread covers LDS bytes [tid*16, +16) of each 8KB block-load.
    // dest slot tid&7 must hold global slot (tid&7)^(row&7), row=(tid>>3)&63.
    const int srow = tid >> 3;            // 0..63
    const int scol = ((tid & 7) ^ ((tid >> 3) & 7)) * 8;
    const bf16_t* Ag = A  + (size_t)(bm + srow) * K + scol;
    const bf16_t* Bg = Bw + (size_t)(bn + srow) * K + scol;

    auto stage = [&](int kt) {
        char* la = smem + (kt % 3) * 32768 + tid * 16;
        char* lb = smem + 98304 + (kt % 3) * 16384 + tid * 16;
#pragma unroll
        for (int bl = 0; bl < 4; ++bl)
            GLD16(Ag + (size_t)(bl * 64) * K + kt * 64, la + bl * 8192);
#pragma unroll
        for (int bl = 0; bl < 2; ++bl)
            GLD16(Bg + (size_t)(bl * 64) * K + kt * 64, lb + bl * 8192);
    };

    f32x4 acc[4][4] = {};

    stage(0); stage(1);                   // 12 loads in flight

    const int frow = lane & 15;
    const int fs   = lane >> 4;           // k-slot within half-row
    const int fx   = lane & 7;            // swizzle xor (== row&7)

    for (int t = 0; t < NT; ++t) {
        if (t < NT - 1) vmwait<6>(); else vmwait<0>();
        __builtin_amdgcn_s_barrier();
        asm volatile("" ::: "memory");

        const char* Ab = smem + (t % 3) * 32768;
        const char* Bb = smem + 98304 + (t % 3) * 16384;

#pragma unroll
        for (int kk = 0; kk < 2; ++kk) {
            bf16x8 af[4], bfr[4];
            const int sp = ((kk * 4 + fs) ^ fx) * 16;
#pragma unroll
            for (int m = 0; m < 4; ++m)
                af[m] = *(const bf16x8*)(Ab + (wm + m * 16 + frow) * 128 + sp);
#pragma unroll
            for (int n = 0; n < 4; ++n)
                bfr[n] = *(const bf16x8*)(Bb + (wn + n * 16 + frow) * 128 + sp);
            if (kk == 1 && t < NT - 2) {
                __builtin_amdgcn_sched_barrier(0);   // pin stage after reads
                stage(t + 2);
            }
            __builtin_amdgcn_s_setprio(1);
#pragma unroll
            for (int m = 0; m < 4; ++m)
#pragma unroll
                for (int n = 0; n < 4; ++n)
                    acc[m][n] = __builtin_amdgcn_mfma_f32_16x16x32_bf16(af[m], bfr[n], acc[m][n], 0, 0, 0);
            __builtin_amdgcn_s_setprio(0);
        }
    }

    // epilogue: C/D frag layout col=lane&15, row=(lane>>4)*4+reg
    const int r0 = (lane >> 4) * 4;
    const int c0 = lane & 15;
#pragma unroll
    for (int m = 0; m < 4; ++m) {
#pragma unroll
        for (int n = 0; n < 4; ++n) {
            const int col = bn + wn + n * 16 + c0;
            float bv = BIAS ? bias[col] : 0.0f;
#pragma unroll
            for (int r = 0; r < 4; ++r) {
                const int row = bm + wm + m * 16 + r0 + r;
                float v = acc[m][n][r] + bv;
                if (F32OUT) ((float*)Cout)[(size_t)row * N + col] = v;
                else        ((bf16_t*)Cout)[(size_t)row * N + col] = (__bf16)v;
            }
        }
    }
}

// ---------------- windowed attention: 8 threads per (b,h,l), one per d-chunk ----------------
__global__ __launch_bounds__(256) void attn_win_kernel(const bf16_t* __restrict__ QKV,
                                                       const float* __restrict__ conn,
                                                       bf16_t* __restrict__ AO)
{
    const int t  = threadIdx.x;
    const int ll = t >> 3;
    const int c  = t & 7;
    const int blk  = blockIdx.x;
    const int lblk = blk & (L_SEQ / 32 - 1);
    const int h    = (blk >> 7) & (NH - 1);
    const int b    = blk >> 11;
    const int l    = lblk * 32 + ll;
    const size_t row = (size_t)b * L_SEQ + l;

    const bf16x8 qv = *(const bf16x8*)(QKV + row * DQKV + h * DHEAD + c * 8);

    float s[7];
#pragma unroll
    for (int o = 0; o < 7; ++o) {
        const int lk = l + o - 3;
        float d = 0.0f;
        if ((unsigned)lk < L_SEQ) {
            const bf16x8 kv = *(const bf16x8*)(QKV + ((size_t)b * L_SEQ + lk) * DQKV
                                               + DM + h * DHEAD + c * 8);
#pragma unroll
            for (int j = 0; j < 8; ++j) d += (float)qv[j] * (float)kv[j];
        }
        s[o] = d;
    }
#pragma unroll
    for (int m = 1; m < 8; m <<= 1) {
#pragma unroll
        for (int o = 0; o < 7; ++o) s[o] += __shfl_xor(s[o], m, 64);
    }

    float mx = -1e30f;
#pragma unroll
    for (int o = 0; o < 7; ++o) { s[o] *= 0.125f; mx = fmaxf(mx, s[o]); }
    float e[7], Z = 0.0f;
#pragma unroll
    for (int o = 0; o < 7; ++o) { e[o] = expf(s[o] - mx); Z += e[o]; }

    float fw[7], fs = 0.0f;
#pragma unroll
    for (int o = 0; o < 7; ++o) { fw[o] = e[o] * conn[h * 7 + o]; fs += fw[o]; }
    const float inv = 1.0f / (fs + 1e-9f * Z);

    float outv[8] = {};
#pragma unroll
    for (int o = 0; o < 7; ++o) {
        const int lk = l + o - 3;
        if ((unsigned)lk >= L_SEQ) continue;
        const float w = fw[o] * inv;
        const bf16x8 vv = *(const bf16x8*)(QKV + ((size_t)b * L_SEQ + lk) * DQKV
                                           + 2 * DM + h * DHEAD + c * 8);
#pragma unroll
        for (int j = 0; j < 8; ++j) outv[j] += w * (float)vv[j];
    }

    bf16x8 ov;
#pragma unroll
    for (int j = 0; j < 8; ++j) ov[j] = (__bf16)outv[j];
    *(bf16x8*)(AO + row * DM + h * DHEAD + c * 8) = ov;
}

// ---------------- launch ----------------
extern "C" void kernel_launch(void* const* d_in, const int* in_sizes, int n_in,
                              void* d_out, int out_size, void* d_ws, size_t ws_size,
                              hipStream_t stream)
{
    const float* x   = (const float*)d_in[0];
    const float* wq  = (const float*)d_in[1];
    const float* wk  = (const float*)d_in[2];
    const float* wv  = (const float*)d_in[3];
    const float* wo  = (const float*)d_in[4];
    const float* bo  = (const float*)d_in[5];
    const float* cw1 = (const float*)d_in[6];
    const float* cb1 = (const float*)d_in[7];
    const float* cw2 = (const float*)d_in[8];
    const float* cb2 = (const float*)d_in[9];
    const float* cw3 = (const float*)d_in[10];
    const float* cb3 = (const float*)d_in[11];
    float* out = (float*)d_out;

    char* ws = (char*)d_ws;
    const size_t MB = 1024 * 1024;
    bf16_t* xb    = (bf16_t*)(ws);             // 16 MB; reused as attention output
    bf16_t* wqkvb = (bf16_t*)(ws + 16 * MB);   // 6 MB   [3072][1024]
    bf16_t* wob   = (bf16_t*)(ws + 22 * MB);   // 2 MB
    bf16_t* QKV   = (bf16_t*)(ws + 24 * MB);   // 48 MB  [8192][3072]
    float*  conn  = (float*)(ws + 72 * MB);    // 448 B

    const int Mrows = NB * L_SEQ;              // 8192

    (void)hipFuncSetAttribute((const void*)gemm3<24, false, false>,
                              hipFuncAttributeMaxDynamicSharedMemorySize, 147456);
    (void)hipFuncSetAttribute((const void*)gemm3<8, true, true>,
                              hipFuncAttributeMaxDynamicSharedMemorySize, 147456);

    cast_f2b_kernel<<<(Mrows * DM / 8 + 255) / 256, 256, 0, stream>>>(x, xb, Mrows * DM / 8);
    cast_w3_kernel<<<(3 * DM * DM / 8) / 256, 256, 0, stream>>>(wq, wk, wv, wqkvb);
    cast_f2b_kernel<<<(DM * DM / 8 + 255) / 256, 256, 0, stream>>>(wo, wob, DM * DM / 8);

    conn_kernel<<<NH, 32, 0, stream>>>(cw1, cb1, cw2, cb2, cw3, cb3, conn);

    // QKV: grid 768 = 3 exact rounds of 256 CUs
    gemm3<24, false, false><<<768, 512, 147456, stream>>>(xb, wqkvb, QKV, nullptr);

    attn_win_kernel<<<(NB * NH * L_SEQ * 8) / 256, 256, 0, stream>>>(QKV, conn, xb);

    // out-proj: grid 256 = 1 exact round
    gemm3<8, true, true><<<256, 512, 147456, stream>>>(xb, wob, out, bo);
}

// Round 5
// 128.224 us; speedup vs baseline: 1.5617x; 1.0058x over previous
//
#include <hip/hip_runtime.h>
#include <hip/hip_bf16.h>
#include <math.h>
#include <stdint.h>

#define L_SEQ 4096
#define NB 2
#define NH 16
#define DHEAD 64
#define DM 1024
#define DQKV 3072

typedef __bf16 bf16_t;
typedef __attribute__((ext_vector_type(8))) __bf16 bf16x8;
typedef __attribute__((ext_vector_type(4))) float f32x4;

#define GLD16(gp, lp) __builtin_amdgcn_global_load_lds(                          \
    (const __attribute__((address_space(1))) void*)(gp),                         \
    (__attribute__((address_space(3))) void*)(lp), 16, 0, 0)

template<int N> __device__ __forceinline__ void vmwait() {
    if constexpr (N == 3)      asm volatile("s_waitcnt vmcnt(3)" ::: "memory");
    else if constexpr (N == 2) asm volatile("s_waitcnt vmcnt(2)" ::: "memory");
    else                       asm volatile("s_waitcnt vmcnt(0)" ::: "memory");
}

// ---------------- cast fp32 -> bf16, 8 elems/thread ----------------
__global__ __launch_bounds__(256) void cast_f2b_kernel(const float* __restrict__ in,
                                                       bf16_t* __restrict__ out, int n8)
{
    int t = blockIdx.x * 256 + threadIdx.x;
    if (t >= n8) return;
    const f32x4* ip = (const f32x4*)(in + (size_t)t * 8);
    f32x4 a = ip[0], b = ip[1];
    bf16x8 o;
    o[0] = (__bf16)a[0]; o[1] = (__bf16)a[1]; o[2] = (__bf16)a[2]; o[3] = (__bf16)a[3];
    o[4] = (__bf16)b[0]; o[5] = (__bf16)b[1]; o[6] = (__bf16)b[2]; o[7] = (__bf16)b[3];
    *(bf16x8*)(out + (size_t)t * 8) = o;
}

__global__ __launch_bounds__(256) void cast_w3_kernel(const float* __restrict__ wq,
                                                      const float* __restrict__ wk,
                                                      const float* __restrict__ wv,
                                                      bf16_t* __restrict__ out)
{
    int t = blockIdx.x * 256 + threadIdx.x;
    const int n1 = DM * DM / 8;
    const float* src; int lt;
    if (t < n1)          { src = wq; lt = t; }
    else if (t < 2 * n1) { src = wk; lt = t - n1; }
    else                 { src = wv; lt = t - 2 * n1; }
    const f32x4* ip = (const f32x4*)(src + (size_t)lt * 8);
    f32x4 a = ip[0], b = ip[1];
    bf16x8 o;
    o[0] = (__bf16)a[0]; o[1] = (__bf16)a[1]; o[2] = (__bf16)a[2]; o[3] = (__bf16)a[3];
    o[4] = (__bf16)b[0]; o[5] = (__bf16)b[1]; o[6] = (__bf16)b[2]; o[7] = (__bf16)b[3];
    *(bf16x8*)(out + (size_t)t * 8) = o;
}

// ---------------- conn[h][w]: per-head positional MLP + softmax ----------------
__device__ __forceinline__ float gelu_exact(float z)
{
    return 0.5f * z * (1.0f + erff(z * 0.7071067811865475f));
}

__global__ void conn_kernel(const float* __restrict__ cw1, const float* __restrict__ cb1,
                            const float* __restrict__ cw2, const float* __restrict__ cb2,
                            const float* __restrict__ cw3, const float* __restrict__ cb3,
                            float* __restrict__ conn)
{
    const int h = blockIdx.x;
    const int j = threadIdx.x;
    __shared__ float h1[7][32];
    __shared__ float h2[7][32];

    for (int w = 0; w < 7; ++w) {
        float pos = (float)w / 6.0f;
        float z = pos * cw1[h * 32 + j] + cb1[h * 32 + j];
        h1[w][j] = gelu_exact(z);
    }
    __syncthreads();
    for (int w = 0; w < 7; ++w) {
        float z = cb2[h * 32 + j];
        for (int i = 0; i < 32; ++i) z += h1[w][i] * cw2[((size_t)h * 32 + j) * 32 + i];
        h2[w][j] = gelu_exact(z);
    }
    __syncthreads();
    if (j == 0) {
        float cwt[7];
        float mx = -1e30f;
        for (int w = 0; w < 7; ++w) {
            float z = cb3[h];
            for (int i = 0; i < 32; ++i) z += h2[w][i] * cw3[h * 32 + i];
            cwt[w] = z;
            mx = fmaxf(mx, z);
        }
        float Z = 0.0f;
        for (int w = 0; w < 7; ++w) { cwt[w] = expf(cwt[w] - mx); Z += cwt[w]; }
        for (int w = 0; w < 7; ++w) conn[h * 7 + w] = cwt[w] / Z;
    }
}

// ---------------- BMxBN bf16 GEMM, BK=32, triple-buffer, fine phases ----------------
// C[M=8192, NOUT] = A @ Bw^T (+bias).  512 thr = 8 waves as 4M x 2N.
// Wave tile (BM/4) x (BN/2); MI=BM/64, NJ=BN/32; 16 (or 8) MFMA per barrier.
// LDS: 3 x (A BM*64 B + B BN*64 B) -> 72 KB (BM=256,BN=128) => 2 blocks/CU.
// Per K-tile t: vmcnt(L) [drain tile t's stages, keep t+1's in flight] ->
// s_barrier -> 8 ds_read_b128 -> stage tile t+2 (L gld_lds, block-uniform) ->
// setprio(1) 16 MFMA setprio(0).  Never vmcnt(0) until the last tile.
// Race proof: stage(t+2) writes buf[(t+2)%3]=buf[(t-1)%3], last read in tile
// t-1; the tile-t barrier orders those reads (completed: their consumers'
// lgkmcnt) before the stage issue.
// Swizzle (64B rows, 4x16B slots): dest slot sd holds source slot
// sd^((row>>1)&3); reads use slot^((row>>1)&3) => 2-way banks (free).
template<int BM, int BN, int NOUT, bool F32OUT, bool BIAS>
__global__ __launch_bounds__(512, 4) void gemm_fp(const bf16_t* __restrict__ A,
                                                  const bf16_t* __restrict__ Bw,
                                                  void* __restrict__ Cout,
                                                  const float* __restrict__ bias)
{
    constexpr int K   = 1024;
    constexpr int NT  = K / 32;            // 32
    constexpr int MI  = BM / 64;
    constexpr int NJ  = BN / 32;
    constexpr int LA  = BM / 128;
    constexpr int LB  = BN / 128;
    constexpr int L   = LA + LB;
    constexpr int ASZ = BM * 64;           // bytes per A K-tile buffer
    constexpr int BSZ = BN * 64;
    constexpr int NTN = NOUT / BN;

    extern __shared__ char smem[];         // A: 3*ASZ @0, B: 3*BSZ @3*ASZ

    const int tid  = threadIdx.x;
    const int lane = tid & 63;
    const int wave = tid >> 6;
    const int wm   = (wave >> 1) * (BM / 4);
    const int wn   = (wave & 1) * (BN / 2);

    // T1: XCD-aware bijective swizzle, bn-fastest (A slice fits per-XCD L2)
    const int nwg = gridDim.x;             // multiple of 8
    int id = blockIdx.x;
    id = (id & 7) * (nwg >> 3) + (id >> 3);
    const int bm = (id / NTN) * BM;
    const int bn = (id % NTN) * BN;

    // staging: thread covers 16B at row tid>>2 (of each 128-row block), slot tid&3;
    // source col pre-swizzled so read-side XOR lands on the right element.
    const int scol = (((tid & 3) ^ ((tid >> 3) & 3)) * 8);   // element offset
    const int srow = tid >> 2;                               // 0..127
    const bf16_t* Ag = A  + (size_t)(bm + srow) * K + scol;
    const bf16_t* Bg = Bw + (size_t)(bn + srow) * K + scol;

    auto stage = [&](int kt) {
        char* la = smem + (kt % 3) * ASZ + tid * 16;
#pragma unroll
        for (int bl = 0; bl < LA; ++bl)
            GLD16(Ag + (size_t)(bl * 128) * K + kt * 32, la + bl * 8192);
        char* lb = smem + 3 * ASZ + (kt % 3) * BSZ + tid * 16;
#pragma unroll
        for (int bl = 0; bl < LB; ++bl)
            GLD16(Bg + (size_t)(bl * 128) * K + kt * 32, lb + bl * 8192);
    };

    f32x4 acc[MI][NJ] = {};

    stage(0); stage(1);                    // 2L loads in flight

    // precomputed swizzled frag byte-offsets (buffer-relative)
    int aoff[MI], boff[NJ];
#pragma unroll
    for (int m = 0; m < MI; ++m) {
        const int r = wm + m * 16 + (lane & 15);
        aoff[m] = r * 64 + (((lane >> 4) ^ ((r >> 1) & 3)) * 16);
    }
#pragma unroll
    for (int n = 0; n < NJ; ++n) {
        const int r = wn + n * 16 + (lane & 15);
        boff[n] = r * 64 + (((lane >> 4) ^ ((r >> 1) & 3)) * 16);
    }

    for (int t = 0; t < NT; ++t) {
        if (t < NT - 1) vmwait<L>(); else vmwait<0>();
        __builtin_amdgcn_s_barrier();
        asm volatile("" ::: "memory");

        const char* Ab = smem + (t % 3) * ASZ;
        const char* Bb = smem + 3 * ASZ + (t % 3) * BSZ;

        bf16x8 af[MI], bfr[NJ];
#pragma unroll
        for (int m = 0; m < MI; ++m) af[m]  = *(const bf16x8*)(Ab + aoff[m]);
#pragma unroll
        for (int n = 0; n < NJ; ++n) bfr[n] = *(const bf16x8*)(Bb + boff[n]);

        if (t + 2 < NT) {
            __builtin_amdgcn_sched_barrier(0);   // reads issue first
            stage(t + 2);
        }

        __builtin_amdgcn_s_setprio(1);
#pragma unroll
        for (int m = 0; m < MI; ++m)
#pragma unroll
            for (int n = 0; n < NJ; ++n)
                acc[m][n] = __builtin_amdgcn_mfma_f32_16x16x32_bf16(af[m], bfr[n], acc[m][n], 0, 0, 0);
        __builtin_amdgcn_s_setprio(0);
    }

    // epilogue: C/D frag layout col=lane&15, row=(lane>>4)*4+reg
    const int r0 = (lane >> 4) * 4;
    const int c0 = lane & 15;
#pragma unroll
    for (int m = 0; m < MI; ++m) {
#pragma unroll
        for (int n = 0; n < NJ; ++n) {
            const int col = bn + wn + n * 16 + c0;
            float bv = BIAS ? bias[col] : 0.0f;
#pragma unroll
            for (int r = 0; r < 4; ++r) {
                const int row = bm + wm + m * 16 + r0 + r;
                float v = acc[m][n][r] + bv;
                if (F32OUT) ((float*)Cout)[(size_t)row * NOUT + col] = v;
                else        ((bf16_t*)Cout)[(size_t)row * NOUT + col] = (__bf16)v;
            }
        }
    }
}

// ---------------- windowed attention: 8 threads per (b,h,l), one per d-chunk ----------------
__global__ __launch_bounds__(256) void attn_win_kernel(const bf16_t* __restrict__ QKV,
                                                       const float* __restrict__ conn,
                                                       bf16_t* __restrict__ AO)
{
    const int t  = threadIdx.x;
    const int ll = t >> 3;
    const int c  = t & 7;
    const int blk  = blockIdx.x;
    const int lblk = blk & (L_SEQ / 32 - 1);
    const int h    = (blk >> 7) & (NH - 1);
    const int b    = blk >> 11;
    const int l    = lblk * 32 + ll;
    const size_t row = (size_t)b * L_SEQ + l;

    const bf16x8 qv = *(const bf16x8*)(QKV + row * DQKV + h * DHEAD + c * 8);

    float s[7];
#pragma unroll
    for (int o = 0; o < 7; ++o) {
        const int lk = l + o - 3;
        float d = 0.0f;
        if ((unsigned)lk < L_SEQ) {
            const bf16x8 kv = *(const bf16x8*)(QKV + ((size_t)b * L_SEQ + lk) * DQKV
                                               + DM + h * DHEAD + c * 8);
#pragma unroll
            for (int j = 0; j < 8; ++j) d += (float)qv[j] * (float)kv[j];
        }
        s[o] = d;
    }
#pragma unroll
    for (int m = 1; m < 8; m <<= 1) {
#pragma unroll
        for (int o = 0; o < 7; ++o) s[o] += __shfl_xor(s[o], m, 64);
    }

    float mx = -1e30f;
#pragma unroll
    for (int o = 0; o < 7; ++o) { s[o] *= 0.125f; mx = fmaxf(mx, s[o]); }
    float e[7], Z = 0.0f;
#pragma unroll
    for (int o = 0; o < 7; ++o) { e[o] = expf(s[o] - mx); Z += e[o]; }

    float fw[7], fs = 0.0f;
#pragma unroll
    for (int o = 0; o < 7; ++o) { fw[o] = e[o] * conn[h * 7 + o]; fs += fw[o]; }
    const float inv = 1.0f / (fs + 1e-9f * Z);

    float outv[8] = {};
#pragma unroll
    for (int o = 0; o < 7; ++o) {
        const int lk = l + o - 3;
        if ((unsigned)lk >= L_SEQ) continue;
        const float w = fw[o] * inv;
        const bf16x8 vv = *(const bf16x8*)(QKV + ((size_t)b * L_SEQ + lk) * DQKV
                                           + 2 * DM + h * DHEAD + c * 8);
#pragma unroll
        for (int j = 0; j < 8; ++j) outv[j] += w * (float)vv[j];
    }

    bf16x8 ov;
#pragma unroll
    for (int j = 0; j < 8; ++j) ov[j] = (__bf16)outv[j];
    *(bf16x8*)(AO + row * DM + h * DHEAD + c * 8) = ov;
}

// ---------------- launch ----------------
extern "C" void kernel_launch(void* const* d_in, const int* in_sizes, int n_in,
                              void* d_out, int out_size, void* d_ws, size_t ws_size,
                              hipStream_t stream)
{
    const float* x   = (const float*)d_in[0];
    const float* wq  = (const float*)d_in[1];
    const float* wk  = (const float*)d_in[2];
    const float* wv  = (const float*)d_in[3];
    const float* wo  = (const float*)d_in[4];
    const float* bo  = (const float*)d_in[5];
    const float* cw1 = (const float*)d_in[6];
    const float* cb1 = (const float*)d_in[7];
    const float* cw2 = (const float*)d_in[8];
    const float* cb2 = (const float*)d_in[9];
    const float* cw3 = (const float*)d_in[10];
    const float* cb3 = (const float*)d_in[11];
    float* out = (float*)d_out;

    char* ws = (char*)d_ws;
    const size_t MB = 1024 * 1024;
    bf16_t* xb    = (bf16_t*)(ws);             // 16 MB; reused as attention output
    bf16_t* wqkvb = (bf16_t*)(ws + 16 * MB);   // 6 MB   [3072][1024]
    bf16_t* wob   = (bf16_t*)(ws + 22 * MB);   // 2 MB
    bf16_t* QKV   = (bf16_t*)(ws + 24 * MB);   // 48 MB  [8192][3072]
    float*  conn  = (float*)(ws + 72 * MB);    // 448 B

    const int Mrows = NB * L_SEQ;              // 8192

    (void)hipFuncSetAttribute((const void*)gemm_fp<256, 128, DQKV, false, false>,
                              hipFuncAttributeMaxDynamicSharedMemorySize, 73728);
    (void)hipFuncSetAttribute((const void*)gemm_fp<128, 128, DM, true, true>,
                              hipFuncAttributeMaxDynamicSharedMemorySize, 49152);

    cast_f2b_kernel<<<(Mrows * DM / 8 + 255) / 256, 256, 0, stream>>>(x, xb, Mrows * DM / 8);
    cast_w3_kernel<<<(3 * DM * DM / 8) / 256, 256, 0, stream>>>(wq, wk, wv, wqkvb);
    cast_f2b_kernel<<<(DM * DM / 8 + 255) / 256, 256, 0, stream>>>(wo, wob, DM * DM / 8);

    conn_kernel<<<NH, 32, 0, stream>>>(cw1, cb1, cw2, cb2, cw3, cb3, conn);

    // QKV: 32 M-tiles x 24 N-tiles = 768 blocks (1.5 capacity rounds at 2/CU)
    gemm_fp<256, 128, DQKV, false, false><<<768, 512, 73728, stream>>>(xb, wqkvb, QKV, nullptr);

    attn_win_kernel<<<(NB * NH * L_SEQ * 8) / 256, 256, 0, stream>>>(QKV, conn, xb);

    // out-proj: 64 x 8 = 512 blocks = exactly 2/CU machine-wide
    gemm_fp<128, 128, DM, true, true><<<512, 512, 49152, stream>>>(xb, wob, out, bo);
}